// Round 8
// baseline (323.476 us; speedup 1.0000x reference)
//
#include <hip/hip_runtime.h>
#include <hip/hip_bf16.h>
#include <math.h>

#define N_NODES 50000
#define N_EDGES 1600000
#define H 64
#define G_GRAPHS 512
#define C_CLS 2
#define BN_EPS 1e-5f
#define NBUCK 196           // buckets of 256 nodes: dst>>8 in [0,196)
#define BUCKCAP 16384       // fixed bucket capacity
#define E4 (N_EDGES / 4)    // 400000
#define SCHUNKS ((E4 + 511) / 512)        // 782 scatter chunks
#define XCHUNKS ((N_NODES + 255) / 256)   // 196
#define IOP 72              // padded LDS row stride (bf16)
#define ZROW N_NODES        // zero-row sentinel index (row 50000)
#define HSTRIDE ((N_NODES + 1) * H)

typedef __attribute__((ext_vector_type(8))) short short8;
typedef __attribute__((ext_vector_type(4))) float floatx4;

__device__ __forceinline__ float bflo(unsigned int u) { return __uint_as_float(u << 16); }
__device__ __forceinline__ float bfhi(unsigned int u) { return __uint_as_float(u & 0xffff0000u); }
__device__ __forceinline__ unsigned int bf16_rne(float f) {
    unsigned int u = __float_as_uint(f);
    u += 0x7fffu + ((u >> 16) & 1u);
    return u >> 16;
}

#define RED3(A) { A += __shfl_xor(A, 8); A += __shfl_xor(A, 16); A += __shfl_xor(A, 32); }
#define RED6(A) { A += __shfl_xor(A, 1); A += __shfl_xor(A, 2); A += __shfl_xor(A, 4); \
                  A += __shfl_xor(A, 8); A += __shfl_xor(A, 16); A += __shfl_xor(A, 32); }

// ---------- fused prep + scatter: edge scatter | wT | x-pack | zero sentinels ----------
__global__ __launch_bounds__(256) void prepscatter_kernel(
    const int* __restrict__ src, const int* __restrict__ dst,
    int* __restrict__ gcnt, int* __restrict__ gpacked,
    const float* __restrict__ w2_0, const float* __restrict__ w1_1,
    const float* __restrict__ w2_1, const float* __restrict__ w1_2,
    const float* __restrict__ w2_2, unsigned short* __restrict__ wt,
    const float* __restrict__ x, uint2* __restrict__ xb,
    __hip_bfloat16* __restrict__ h1, __hip_bfloat16* __restrict__ h2) {
    int b = blockIdx.x, t = threadIdx.x;
    if (b < SCHUNKS) {
        __shared__ int bh[NBUCK];
        if (t < NBUCK) bh[t] = 0;
        __syncthreads();
        int base = b * 512;
        int pkA[4], bkA[4], lrA[4]; bool vA = false;
        int pkB[4], bkB[4], lrB[4]; bool vB = false;
        {
            int i = base + t;
            if (i < E4) {
                vA = true;
                int4 s4 = ((const int4*)src)[i];
                int4 d4 = ((const int4*)dst)[i];
                bkA[0] = d4.x >> 8; pkA[0] = ((d4.x & 255) << 16) | s4.x; lrA[0] = atomicAdd(&bh[bkA[0]], 1);
                bkA[1] = d4.y >> 8; pkA[1] = ((d4.y & 255) << 16) | s4.y; lrA[1] = atomicAdd(&bh[bkA[1]], 1);
                bkA[2] = d4.z >> 8; pkA[2] = ((d4.z & 255) << 16) | s4.z; lrA[2] = atomicAdd(&bh[bkA[2]], 1);
                bkA[3] = d4.w >> 8; pkA[3] = ((d4.w & 255) << 16) | s4.w; lrA[3] = atomicAdd(&bh[bkA[3]], 1);
            }
        }
        {
            int i = base + 256 + t;
            if (i < E4) {
                vB = true;
                int4 s4 = ((const int4*)src)[i];
                int4 d4 = ((const int4*)dst)[i];
                bkB[0] = d4.x >> 8; pkB[0] = ((d4.x & 255) << 16) | s4.x; lrB[0] = atomicAdd(&bh[bkB[0]], 1);
                bkB[1] = d4.y >> 8; pkB[1] = ((d4.y & 255) << 16) | s4.y; lrB[1] = atomicAdd(&bh[bkB[1]], 1);
                bkB[2] = d4.z >> 8; pkB[2] = ((d4.z & 255) << 16) | s4.z; lrB[2] = atomicAdd(&bh[bkB[2]], 1);
                bkB[3] = d4.w >> 8; pkB[3] = ((d4.w & 255) << 16) | s4.w; lrB[3] = atomicAdd(&bh[bkB[3]], 1);
            }
        }
        __syncthreads();
        if (t < NBUCK) {
            int c = bh[t];
            bh[t] = c ? atomicAdd(&gcnt[t], c) : 0;
        }
        __syncthreads();
        if (vA) {
#pragma unroll
            for (int q = 0; q < 4; q++) gpacked[bkA[q] * BUCKCAP + bh[bkA[q]] + lrA[q]] = pkA[q];
        }
        if (vB) {
#pragma unroll
            for (int q = 0; q < 4; q++) gpacked[bkB[q] * BUCKCAP + bh[bkB[q]] + lrB[q]] = pkB[q];
        }
    } else if (b < SCHUNKS + 5) {
        int w_id = b - SCHUNKS;
        const float* w = (w_id == 0) ? w2_0 : (w_id == 1) ? w1_1 : (w_id == 2) ? w2_1
                         : (w_id == 3) ? w1_2 : w2_2;
        unsigned short* o = wt + w_id * (H * H);
        for (int idx = t; idx < H * H; idx += 256) {
            int k = idx >> 6, jc = idx & 63;
            o[jc * H + k] = (unsigned short)bf16_rne(w[idx]);
        }
    } else if (b < SCHUNKS + 5 + XCHUNKS) {
        int node = (b - SCHUNKS - 5) * 256 + t;
        if (node < N_NODES) {
            uint2 p;
            p.x = bf16_rne(x[node * 3 + 0]) | (bf16_rne(x[node * 3 + 1]) << 16);
            p.y = bf16_rne(x[node * 3 + 2]);
            xb[node] = p;
        }
    } else {
        // zero sentinels: h1/h2 row ZROW (128 B each), xb[ZROW]
        uint4 z = {0u, 0u, 0u, 0u};
        if (t < 8) ((uint4*)((unsigned short*)h1 + (size_t)ZROW * H))[t] = z;
        else if (t < 16) ((uint4*)((unsigned short*)h2 + (size_t)ZROW * H))[t - 8] = z;
        else if (t == 16) { uint2 zz; zz.x = 0u; zz.y = 0u; xb[ZROW] = zz; }
    }
}

// ---------- CSR pass 2: per-bucket local CSR ----------
__global__ __launch_bounds__(256) void bcsr_kernel(const int* __restrict__ gpacked,
                                                   const int* __restrict__ gcnt,
                                                   int* __restrict__ row_start,
                                                   int* __restrict__ edge_src) {
    __shared__ int cnt[256];
    __shared__ int pref[256];
    int b = blockIdx.x;
    int t = threadIdx.x;

    int v = (t < NBUCK) ? gcnt[t] : 0;
    pref[t] = v;
    __syncthreads();
    for (int off = 1; off < 256; off <<= 1) {
        int u = 0;
        if (t >= off) u = pref[t - off];
        __syncthreads();
        if (t >= off) pref[t] += u;
        __syncthreads();
    }
    int bs = (b > 0) ? pref[b - 1] : 0;
    int cnt_b = gcnt[b];
    if (b == 0 && t == 0) row_start[N_NODES] = N_EDGES;
    __syncthreads();

    const int* gp = gpacked + (size_t)b * BUCKCAP;
    cnt[t] = 0;
    __syncthreads();
    for (int i = t; i < cnt_b; i += 256) atomicAdd(&cnt[gp[i] >> 16], 1);
    __syncthreads();
    int c = cnt[t];
    pref[t] = c;
    __syncthreads();
    for (int off = 1; off < 256; off <<= 1) {
        int u = 0;
        if (t >= off) u = pref[t - off];
        __syncthreads();
        if (t >= off) pref[t] += u;
        __syncthreads();
    }
    int excl = pref[t] - c;
    int node = b * 256 + t;
    if (node < N_NODES) row_start[node] = bs + excl;
    cnt[t] = excl;
    __syncthreads();
    for (int i = t; i < cnt_b; i += 256) {
        int p = gp[i];
        int pos = atomicAdd(&cnt[p >> 16], 1);
        edge_src[bs + pos] = p & 0xffff;
    }
}

// ---------- layer 1: interleaved branch-free sentinel gather, wave0 MFMA lin2, pooled ----------
__global__ __launch_bounds__(512) void gin1_fused16_kernel(
    const float* __restrict__ x, const uint2* __restrict__ xb,
    const int* __restrict__ row_start, const int* __restrict__ edge_src,
    const float* __restrict__ w1, const float* __restrict__ b1,
    const float* __restrict__ bn_g, const float* __restrict__ bn_b,
    const float* __restrict__ bn_m, const float* __restrict__ bn_v,
    const unsigned short* __restrict__ w2t, const float* __restrict__ b2,
    __hip_bfloat16* __restrict__ hout, const int* __restrict__ batch,
    float* __restrict__ pool) {
    __shared__ unsigned short s_mid[16 * IOP];
    __shared__ int s_bat[16];

    int tid = threadIdx.x;
    int wave = tid >> 6, j = tid & 63;
    int nodebase = blockIdx.x * 16;     // 3125 blocks x 16 = 50000 exact
    if (tid < 16) s_bat[tid] = batch[nodebase + tid];

    float wj0 = w1[j], wj1 = w1[H + j], wj2 = w1[2 * H + j];
    float sc = rsqrtf(bn_v[j] + BN_EPS) * bn_g[j];
    float sh = bn_b[j] - bn_m[j] * sc;
    float bj = b1[j];

    // phase A: both nodes interleaved, unconditional loads (xb[ZROW] = 0)
    int n0 = nodebase + wave * 2;
    int rsA = row_start[n0];
    int rsB = row_start[n0 + 1];
    int reB = row_start[n0 + 2];
    int cntA = rsB - rsA, cntB = reB - rsB;
    int cmax = max(cntA, cntB);

    float a0 = 0.f, a1 = 0.f, a2 = 0.f;
    float c0 = 0.f, c1 = 0.f, c2 = 0.f;
    for (int base = 0; base < cmax; base += 64) {
        int iA = base + j;
        int svA = (iA < cntA) ? edge_src[rsA + iA] : ZROW;
        int svB = (iA < cntB) ? edge_src[rsB + iA] : ZROW;
        uint2 pA = xb[svA];
        uint2 pB = xb[svB];
        a0 += bflo(pA.x); a1 += bfhi(pA.x); a2 += bflo(pA.y);
        c0 += bflo(pB.x); c1 += bfhi(pB.x); c2 += bflo(pB.y);
    }
    RED6(a0) RED6(c0) RED6(a1) RED6(c1) RED6(a2) RED6(c2)
    {
        float in0 = a0 + x[n0 * 3 + 0];
        float in1 = a1 + x[n0 * 3 + 1];
        float in2 = a2 + x[n0 * 3 + 2];
        float m = bj + in0 * wj0 + in1 * wj1 + in2 * wj2;
        m = fmaxf(m * sc + sh, 0.f);
        s_mid[(wave * 2) * IOP + j] = (unsigned short)bf16_rne(m);
    }
    {
        int n1 = n0 + 1;
        float in0 = c0 + x[n1 * 3 + 0];
        float in1 = c1 + x[n1 * 3 + 1];
        float in2 = c2 + x[n1 * 3 + 2];
        float m = bj + in0 * wj0 + in1 * wj1 + in2 * wj2;
        m = fmaxf(m * sc + sh, 0.f);
        s_mid[(wave * 2 + 1) * IOP + j] = (unsigned short)bf16_rne(m);
    }
    __syncthreads();

    // phase B: wave 0 computes relu(mid@w2+b2) for all 16 nodes, stores + pools
    if (wave == 0) {
        int quad = j >> 4, l15 = j & 15;
        float bb2[4];
#pragma unroll
        for (int jt = 0; jt < 4; jt++) bb2[jt] = b2[jt * 16 + l15];

        short8 m0 = *(const short8*)&s_mid[l15 * IOP + quad * 8];
        short8 m1 = *(const short8*)&s_mid[l15 * IOP + quad * 8 + 32];
        int bq0 = s_bat[quad * 4], bq3 = s_bat[quad * 4 + 3];
#pragma unroll
        for (int jt = 0; jt < 4; jt++) {
            short8 b0 = *(const short8*)&w2t[(jt * 16 + l15) * H + quad * 8];
            short8 bv = *(const short8*)&w2t[(jt * 16 + l15) * H + quad * 8 + 32];
            floatx4 c = {0.f, 0.f, 0.f, 0.f};
            c = __builtin_amdgcn_mfma_f32_16x16x32_bf16(m0, b0, c, 0, 0, 0);
            c = __builtin_amdgcn_mfma_f32_16x16x32_bf16(m1, bv, c, 0, 0, 0);
            float vv[4];
#pragma unroll
            for (int r = 0; r < 4; r++) {
                float v = fmaxf(c[r] + bb2[jt], 0.f);
                vv[r] = v;
                s_mid[(quad * 4 + r) * IOP + jt * 16 + l15] = (unsigned short)bf16_rne(v);
            }
            int jj = jt * 16 + l15;
            if (bq0 == bq3) {
                atomicAdd(&pool[bq0 * 192 + jj], (vv[0] + vv[1]) + (vv[2] + vv[3]));
            } else {
                atomicAdd(&pool[s_bat[quad * 4 + 0] * 192 + jj], vv[0]);
                atomicAdd(&pool[s_bat[quad * 4 + 1] * 192 + jj], vv[1]);
                atomicAdd(&pool[s_bat[quad * 4 + 2] * 192 + jj], vv[2]);
                atomicAdd(&pool[s_bat[quad * 4 + 3] * 192 + jj], vv[3]);
            }
        }
        unsigned short* ho = (unsigned short*)hout;
#pragma unroll
        for (int cc = 0; cc < 2; cc++) {
            int r = cc * 8 + (j >> 3);
            short8 v = *(const short8*)&s_mid[r * IOP + (j & 7) * 8];
            *(short8*)(ho + (size_t)(nodebase + r) * H + (j & 7) * 8) = v;
        }
    }
}

#define ACCA(R) { \
    a0 += bflo(R.x); a1 += bfhi(R.x); a2 += bflo(R.y); a3 += bfhi(R.y); \
    a4 += bflo(R.z); a5 += bfhi(R.z); a6 += bflo(R.w); a7 += bfhi(R.w); }
#define ACCB(R) { \
    c0 += bflo(R.x); c1 += bfhi(R.x); c2 += bflo(R.y); c3 += bfhi(R.y); \
    c4 += bflo(R.z); c5 += bfhi(R.z); c6 += bflo(R.w); c7 += bfhi(R.w); }
#define GLOAD(R, sv, kk) { int s_ = __shfl(sv, (kk) + o); \
    R = *(const uint4*)(hb + (size_t)s_ * 128 + jo * 16); }

// ---------- layers 2/3: straight-line branch-free sentinel gather (16 loads in flight) ----------
__global__ __launch_bounds__(512) void gin_fused16_kernel(
    const __hip_bfloat16* __restrict__ hin, const int* __restrict__ row_start,
    const int* __restrict__ edge_src,
    const unsigned short* __restrict__ w1t, const float* __restrict__ b1,
    const float* __restrict__ bn_g, const float* __restrict__ bn_b,
    const float* __restrict__ bn_m, const float* __restrict__ bn_v,
    const unsigned short* __restrict__ w2t, const float* __restrict__ b2,
    __hip_bfloat16* __restrict__ hout, const int* __restrict__ batch,
    float* __restrict__ pool) {
    __shared__ unsigned short s_xs[16 * IOP];
    __shared__ unsigned short s_mid[16 * IOP];
    __shared__ int s_bat[16];

    int tid = threadIdx.x;
    int wave = tid >> 6, j = tid & 63;
    int o = j >> 3, jo = j & 7;
    int nodebase = blockIdx.x * 16;
    if (tid < 16) s_bat[tid] = batch[nodebase + tid];

    const char* hb = (const char*)hin;

    // phase A: wave's 2 nodes (A,B), 64-edge chunk processed branch-free:
    // out-of-range slots read the zero row (exact +0); all 16 loads unconditional.
    int n0 = nodebase + wave * 2;
    int rsA = row_start[n0];
    int rsB = row_start[n0 + 1];
    int reB = row_start[n0 + 2];
    int cntA = rsB - rsA, cntB = reB - rsB;
    int cmax = max(cntA, cntB);

    float a0 = 0.f, a1 = 0.f, a2 = 0.f, a3 = 0.f, a4 = 0.f, a5 = 0.f, a6 = 0.f, a7 = 0.f;
    float c0 = 0.f, c1 = 0.f, c2 = 0.f, c3 = 0.f, c4 = 0.f, c5 = 0.f, c6 = 0.f, c7 = 0.f;

    for (int base = 0; base < cmax; base += 64) {
        int iA = base + j;
        int svA = (iA < cntA) ? edge_src[rsA + iA] : ZROW;
        int svB = (iA < cntB) ? edge_src[rsB + iA] : ZROW;
        uint4 RA0, RA1, RA2, RA3, RA4, RA5, RA6, RA7;
        uint4 RB0, RB1, RB2, RB3, RB4, RB5, RB6, RB7;
        GLOAD(RA0, svA, 0)  GLOAD(RB0, svB, 0)
        GLOAD(RA1, svA, 8)  GLOAD(RB1, svB, 8)
        GLOAD(RA2, svA, 16) GLOAD(RB2, svB, 16)
        GLOAD(RA3, svA, 24) GLOAD(RB3, svB, 24)
        GLOAD(RA4, svA, 32) GLOAD(RB4, svB, 32)
        GLOAD(RA5, svA, 40) GLOAD(RB5, svB, 40)
        GLOAD(RA6, svA, 48) GLOAD(RB6, svB, 48)
        GLOAD(RA7, svA, 56) GLOAD(RB7, svB, 56)
        ACCA(RA0) ACCB(RB0)
        ACCA(RA1) ACCB(RB1)
        ACCA(RA2) ACCB(RB2)
        ACCA(RA3) ACCB(RB3)
        ACCA(RA4) ACCB(RB4)
        ACCA(RA5) ACCB(RB5)
        ACCA(RA6) ACCB(RB6)
        ACCA(RA7) ACCB(RB7)
    }
    // butterfly over the octet dim (A and B chains interleave)
    RED3(a0) RED3(c0) RED3(a1) RED3(c1) RED3(a2) RED3(c2) RED3(a3) RED3(c3)
    RED3(a4) RED3(c4) RED3(a5) RED3(c5) RED3(a6) RED3(c6) RED3(a7) RED3(c7)

    if (o < 2) {
        int nl = wave * 2 + o;
        float r0 = (o == 0) ? a0 : c0, r1 = (o == 0) ? a1 : c1;
        float r2 = (o == 0) ? a2 : c2, r3 = (o == 0) ? a3 : c3;
        float r4 = (o == 0) ? a4 : c4, r5 = (o == 0) ? a5 : c5;
        float r6 = (o == 0) ? a6 : c6, r7 = (o == 0) ? a7 : c7;
        uint4 raw = *(const uint4*)(hb + (size_t)(nodebase + nl) * 128 + jo * 16);
        r0 += bflo(raw.x); r1 += bfhi(raw.x);
        r2 += bflo(raw.y); r3 += bfhi(raw.y);
        r4 += bflo(raw.z); r5 += bfhi(raw.z);
        r6 += bflo(raw.w); r7 += bfhi(raw.w);
        uint4 ov;
        ov.x = bf16_rne(r0) | (bf16_rne(r1) << 16);
        ov.y = bf16_rne(r2) | (bf16_rne(r3) << 16);
        ov.z = bf16_rne(r4) | (bf16_rne(r5) << 16);
        ov.w = bf16_rne(r6) | (bf16_rne(r7) << 16);
        *(uint4*)&s_xs[nl * IOP + jo * 8] = ov;
    }
    __syncthreads();

    // phase B: wave 0 runs the full MLP for all 16 nodes, stores + pools
    if (wave == 0) {
        int quad = j >> 4, l15 = j & 15;
        float scl[4], sht[4], bb1[4], bb2[4];
#pragma unroll
        for (int jt = 0; jt < 4; jt++) {
            int jj = jt * 16 + l15;
            float sc = rsqrtf(bn_v[jj] + BN_EPS) * bn_g[jj];
            scl[jt] = sc;
            sht[jt] = bn_b[jj] - bn_m[jj] * sc;
            bb1[jt] = b1[jj];
            bb2[jt] = b2[jj];
        }
        short8 a0v = *(const short8*)&s_xs[l15 * IOP + quad * 8];
        short8 a1v = *(const short8*)&s_xs[l15 * IOP + quad * 8 + 32];
#pragma unroll
        for (int jt = 0; jt < 4; jt++) {
            short8 b0 = *(const short8*)&w1t[(jt * 16 + l15) * H + quad * 8];
            short8 bv = *(const short8*)&w1t[(jt * 16 + l15) * H + quad * 8 + 32];
            floatx4 c = {0.f, 0.f, 0.f, 0.f};
            c = __builtin_amdgcn_mfma_f32_16x16x32_bf16(a0v, b0, c, 0, 0, 0);
            c = __builtin_amdgcn_mfma_f32_16x16x32_bf16(a1v, bv, c, 0, 0, 0);
#pragma unroll
            for (int r = 0; r < 4; r++) {
                float v = (c[r] + bb1[jt]) * scl[jt] + sht[jt];
                v = fmaxf(v, 0.f);
                s_mid[(quad * 4 + r) * IOP + jt * 16 + l15] = (unsigned short)bf16_rne(v);
            }
        }
        short8 m0 = *(const short8*)&s_mid[l15 * IOP + quad * 8];
        short8 m1 = *(const short8*)&s_mid[l15 * IOP + quad * 8 + 32];
        int bq0 = s_bat[quad * 4], bq3 = s_bat[quad * 4 + 3];
#pragma unroll
        for (int jt = 0; jt < 4; jt++) {
            short8 b0 = *(const short8*)&w2t[(jt * 16 + l15) * H + quad * 8];
            short8 bv = *(const short8*)&w2t[(jt * 16 + l15) * H + quad * 8 + 32];
            floatx4 c = {0.f, 0.f, 0.f, 0.f};
            c = __builtin_amdgcn_mfma_f32_16x16x32_bf16(m0, b0, c, 0, 0, 0);
            c = __builtin_amdgcn_mfma_f32_16x16x32_bf16(m1, bv, c, 0, 0, 0);
            float vv[4];
#pragma unroll
            for (int r = 0; r < 4; r++) {
                float v = fmaxf(c[r] + bb2[jt], 0.f);
                vv[r] = v;
                s_xs[(quad * 4 + r) * IOP + jt * 16 + l15] = (unsigned short)bf16_rne(v);
            }
            int jj = jt * 16 + l15;
            if (bq0 == bq3) {
                atomicAdd(&pool[bq0 * 192 + jj], (vv[0] + vv[1]) + (vv[2] + vv[3]));
            } else {
                atomicAdd(&pool[s_bat[quad * 4 + 0] * 192 + jj], vv[0]);
                atomicAdd(&pool[s_bat[quad * 4 + 1] * 192 + jj], vv[1]);
                atomicAdd(&pool[s_bat[quad * 4 + 2] * 192 + jj], vv[2]);
                atomicAdd(&pool[s_bat[quad * 4 + 3] * 192 + jj], vv[3]);
            }
        }
        unsigned short* ho = (unsigned short*)hout;
#pragma unroll
        for (int cc = 0; cc < 2; cc++) {
            int r = cc * 8 + (j >> 3);
            short8 v = *(const short8*)&s_xs[r * IOP + (j & 7) * 8];
            *(short8*)(ho + (size_t)(nodebase + r) * H + (j & 7) * 8) = v;
        }
    }
}

// ---------- head ----------
__global__ __launch_bounds__(192) void head_kernel(
    const float* __restrict__ pool,
    const float* __restrict__ lin1_w, const float* __restrict__ lin1_b,
    const float* __restrict__ lin2_w, const float* __restrict__ lin2_b,
    float* __restrict__ out) {
    __shared__ float s_row[3 * H];
    __shared__ float s_mid[3 * H];
    __shared__ float s_z[C_CLS];

    int g = blockIdx.x;
    int j = threadIdx.x;
    s_row[j] = pool[g * 192 + j];
    __syncthreads();

    float acc = lin1_b[j];
    for (int k = 0; k < 3 * H; k++) acc += s_row[k] * lin1_w[k * (3 * H) + j];
    s_mid[j] = fmaxf(acc, 0.f);
    __syncthreads();

    if (j < C_CLS) {
        float z = lin2_b[j];
        for (int k = 0; k < 3 * H; k++) z += s_mid[k] * lin2_w[k * C_CLS + j];
        s_z[j] = z;
    }
    __syncthreads();
    if (j < C_CLS) {
        float z0 = s_z[0], z1 = s_z[1];
        float mx = fmaxf(z0, z1);
        float lse = mx + logf(expf(z0 - mx) + expf(z1 - mx));
        out[g * C_CLS + j] = s_z[j];
        out[G_GRAPHS * C_CLS + g * C_CLS + j] = s_z[j] - lse;
    }
}

extern "C" void kernel_launch(void* const* d_in, const int* in_sizes, int n_in,
                              void* d_out, int out_size, void* d_ws, size_t ws_size,
                              hipStream_t stream) {
    const float* x = (const float*)d_in[0];
    const float* cw1[3], *cb1[3], *cg[3], *cbb[3], *cm[3], *cv[3], *cw2[3], *cb2[3];
    for (int l = 0; l < 3; l++) {
        int b = 1 + 8 * l;
        cw1[l] = (const float*)d_in[b + 0];
        cb1[l] = (const float*)d_in[b + 1];
        cg[l]  = (const float*)d_in[b + 2];
        cbb[l] = (const float*)d_in[b + 3];
        cm[l]  = (const float*)d_in[b + 4];
        cv[l]  = (const float*)d_in[b + 5];
        cw2[l] = (const float*)d_in[b + 6];
        cb2[l] = (const float*)d_in[b + 7];
    }
    const float* lin1_w = (const float*)d_in[25];
    const float* lin1_b = (const float*)d_in[26];
    const float* lin2_w = (const float*)d_in[27];
    const float* lin2_b = (const float*)d_in[28];
    const int* edge_index = (const int*)d_in[29];
    const int* batch = (const int*)d_in[30];
    const int* src = edge_index;
    const int* dst = edge_index + N_EDGES;
    float* out = (float*)d_out;

    // workspace layout (gcnt, pool contiguous -> single memset)
    int* edge_src = (int*)d_ws;                      // E
    int* gpacked = edge_src + N_EDGES;               // NBUCK*BUCKCAP (12.8 MB)
    int* gcnt = gpacked + (size_t)NBUCK * BUCKCAP;   // NBUCK
    float* pool = (float*)(gcnt + NBUCK);            // G*192
    int* row_start = (int*)(pool + G_GRAPHS * 3 * H);// N+2
    uintptr_t hp = (uintptr_t)(row_start + N_NODES + 2);
    hp = (hp + 127) & ~(uintptr_t)127;
    unsigned short* wt = (unsigned short*)hp;        // 5 * H*H bf16
    uint2* xb = (uint2*)(wt + 5 * H * H);            // N+1 (zero sentinel at ZROW)
    __hip_bfloat16* h1 = (__hip_bfloat16*)(xb + N_NODES + 1);  // (N+1)*H each
    __hip_bfloat16* h2 = h1 + (size_t)HSTRIDE;
    __hip_bfloat16* h3 = h2 + (size_t)HSTRIDE;

    const unsigned short* w2t_0 = wt + 0 * H * H;
    const unsigned short* w1t_1 = wt + 1 * H * H;
    const unsigned short* w2t_1 = wt + 2 * H * H;
    const unsigned short* w1t_2 = wt + 3 * H * H;
    const unsigned short* w2t_2 = wt + 4 * H * H;

    // ---- prep + CSR build ----
    hipMemsetAsync(gcnt, 0, NBUCK * sizeof(int) + (size_t)G_GRAPHS * 3 * H * sizeof(float),
                   stream);
    prepscatter_kernel<<<SCHUNKS + 5 + XCHUNKS + 1, 256, 0, stream>>>(
        src, dst, gcnt, gpacked, cw2[0], cw1[1], cw2[1], cw1[2], cw2[2], wt, x, xb, h1, h2);
    bcsr_kernel<<<NBUCK, 256, 0, stream>>>(gpacked, gcnt, row_start, edge_src);

    const int fgrid = N_NODES / 16;   // 3125, exact

    // ---- layer 1 ----
    gin1_fused16_kernel<<<fgrid, 512, 0, stream>>>(x, xb, row_start, edge_src,
        cw1[0], cb1[0], cg[0], cbb[0], cm[0], cv[0], w2t_0, cb2[0], h1, batch, pool);
    // ---- layer 2 ----
    gin_fused16_kernel<<<fgrid, 512, 0, stream>>>(h1, row_start, edge_src,
        w1t_1, cb1[1], cg[1], cbb[1], cm[1], cv[1], w2t_1, cb2[1], h2, batch, pool + 64);
    // ---- layer 3 ----
    gin_fused16_kernel<<<fgrid, 512, 0, stream>>>(h2, row_start, edge_src,
        w1t_2, cb1[2], cg[2], cbb[2], cm[2], cv[2], w2t_2, cb2[2], h3, batch, pool + 128);
    // ---- head ----
    head_kernel<<<G_GRAPHS, 3 * H, 0, stream>>>(pool,
        lin1_w, lin1_b, lin2_w, lin2_b, out);
}